// Round 1
// baseline (264.579 us; speedup 1.0000x reference)
//
#include <hip/hip_runtime.h>
#include <hip/hip_bf16.h>

// AdaptiveMultiSiren: 2048 blocks x 1024 coords, 3->64->64->64->3, sin(30*) acts.
// Layers 1,2 via bf16 MFMA (f32 accum); layer 0 via bf16 hi/lo split MFMA
// (full f32-equivalent precision where omega0=30 amplifies rounding);
// layer 3 bf16 MFMA (attenuated by tiny last-layer weights).
// omega0/(2*pi) is folded into staged weights/biases so activation = fract+v_sin.

namespace {

constexpr int   TPTS = 1024;
constexpr float C30  = 30.0f * 0.15915494309189535f; // omega0 / (2*pi)

typedef float        f32x4 __attribute__((ext_vector_type(4)));
typedef short        s16x8 __attribute__((ext_vector_type(8)));
typedef unsigned int u32x4 __attribute__((ext_vector_type(4)));
typedef unsigned int u32x2 __attribute__((ext_vector_type(2)));

__device__ __forceinline__ unsigned short bfr(float x) {
    __hip_bfloat16 h = __float2bfloat16(x);
    unsigned short u;
    __builtin_memcpy(&u, &h, sizeof(u));
    return u;
}
__device__ __forceinline__ float bf2f(unsigned short u) {
    unsigned int w = (unsigned int)u << 16;
    float f;
    __builtin_memcpy(&f, &w, sizeof(f));
    return f;
}
// input in revolutions; v_sin computes sin(2*pi*x), fract keeps it in-range
__device__ __forceinline__ float sin_rev(float r) {
    return __builtin_amdgcn_sinf(__builtin_amdgcn_fractf(r));
}

// acc[ni][tj]: D[n][t] frags. Apply sin, pack 4 consecutive n as bf16, store to
// swizzled row-major lh[t][n].
__device__ __forceinline__ void act_store(const f32x4 (&acc)[4][4],
                                          unsigned char* lh,
                                          int tw, int l15, int kg) {
    const unsigned swz = (unsigned)(l15 & 7) << 4;
    #pragma unroll
    for (int ni = 0; ni < 4; ++ni) {
        #pragma unroll
        for (int tj = 0; tj < 4; ++tj) {
            f32x4 a = acc[ni][tj];
            unsigned short s0 = bfr(sin_rev(a[0]));
            unsigned short s1 = bfr(sin_rev(a[1]));
            unsigned short s2 = bfr(sin_rev(a[2]));
            unsigned short s3 = bfr(sin_rev(a[3]));
            u32x2 p;
            p[0] = (unsigned)s0 | ((unsigned)s1 << 16);
            p[1] = (unsigned)s2 | ((unsigned)s3 << 16);
            const int trow = tw + tj * 16 + l15;
            *(u32x2*)(lh + trow * 128 +
                      (((unsigned)(ni * 32 + kg * 8)) ^ swz)) = p;
        }
    }
}

// z[n][t] = C30*b[n] + sum_k Wt[n][k] * h[t][k]   (both staged bf16 in LDS)
__device__ __forceinline__ void hidden_layer(f32x4 (&acc)[4][4],
                                             const unsigned char* lw,
                                             const unsigned char* lh,
                                             const float* lb,
                                             int tw, int l15, int kg) {
    const unsigned swz = (unsigned)(l15 & 7) << 4;
    #pragma unroll
    for (int ni = 0; ni < 4; ++ni) {
        f32x4 bv = *(const f32x4*)(lb + ni * 16 + kg * 4);
        #pragma unroll
        for (int tj = 0; tj < 4; ++tj) acc[ni][tj] = bv;
    }
    #pragma unroll
    for (int ks = 0; ks < 2; ++ks) {
        const unsigned ko = (unsigned)(ks * 64 + kg * 16);
        s16x8 wf[4], hf[4];
        #pragma unroll
        for (int ni = 0; ni < 4; ++ni)
            wf[ni] = *(const s16x8*)(lw + (ni * 16 + l15) * 128 + (ko ^ swz));
        #pragma unroll
        for (int tj = 0; tj < 4; ++tj)
            hf[tj] = *(const s16x8*)(lh + (tw + tj * 16 + l15) * 128 + (ko ^ swz));
        #pragma unroll
        for (int ni = 0; ni < 4; ++ni) {
            #pragma unroll
            for (int tj = 0; tj < 4; ++tj)
                acc[ni][tj] = __builtin_amdgcn_mfma_f32_16x16x32_bf16(
                    wf[ni], hf[tj], acc[ni][tj], 0, 0, 0);
        }
    }
}

} // namespace

__global__ __launch_bounds__(256) void siren_fused(
    const float* __restrict__ inp, const int* __restrict__ indices,
    const float* __restrict__ W0, const float* __restrict__ b0,
    const float* __restrict__ W1, const float* __restrict__ b1,
    const float* __restrict__ W2, const float* __restrict__ b2,
    const float* __restrict__ W3, const float* __restrict__ b3,
    float* __restrict__ out)
{
    __shared__ __align__(16) unsigned char lds[54016];
    unsigned char* const lh  = lds;             // 256 x 128B : h tile (bf16, swz)
    unsigned char* const lw1 = lds + 32768;     // 64 x 128B  : C30*W1^T bf16, swz
    unsigned char* const lw2 = lds + 40960;     // 64 x 128B  : C30*W2^T bf16, swz
    unsigned char* const lw3 = lds + 49152;     // 16 x 128B  : W3^T bf16 (rows 0..2)
    unsigned char* const lw0 = lds + 51200;     // 64 x 32B   : layer0 hi/lo expand
    float*         const lbias = (float*)(lds + 53248); // 3 x 64 f32 (C30*b0,b1,b2)

    const int tid  = threadIdx.x;
    const int lane = tid & 63;
    const int wid  = tid >> 6;
    const int l15  = lane & 15;
    const int kg   = lane >> 4;
    const int bid  = blockIdx.x;

    const int idx = __builtin_amdgcn_readfirstlane(indices[bid]);

    const float* const W0g = W0 + (size_t)idx * 192;
    const float* const b0g = b0 + (size_t)idx * 64;
    const float* const W1g = W1 + (size_t)idx * 4096;
    const float* const b1g = b1 + (size_t)idx * 64;
    const float* const W2g = W2 + (size_t)idx * 4096;
    const float* const b2g = b2 + (size_t)idx * 64;
    const float* const W3g = W3 + (size_t)idx * 192;
    const float* const b3g = b3 + (size_t)idx * 3;

    // ------------- prologue: stage weights/biases to LDS -------------
    {
        const int n  = tid & 63;
        const int kc = (tid >> 6) * 16;          // k-chunk of 16
        const unsigned rowb = (unsigned)n * 128u;
        const unsigned swzn = (unsigned)(n & 7) << 4;
        #pragma unroll
        for (int w = 0; w < 2; ++w) {
            const float* Wg = w ? W2g : W1g;
            unsigned char* lw = w ? lw2 : lw1;
            unsigned int q[8];
            #pragma unroll
            for (int j = 0; j < 8; ++j) {
                unsigned short e0 = bfr(Wg[(kc + 2 * j    ) * 64 + n] * C30);
                unsigned short e1 = bfr(Wg[(kc + 2 * j + 1) * 64 + n] * C30);
                q[j] = (unsigned)e0 | ((unsigned)e1 << 16);
            }
            u32x4 q0 = {q[0], q[1], q[2], q[3]};
            u32x4 q1 = {q[4], q[5], q[6], q[7]};
            *(u32x4*)(lw + rowb + (((unsigned)(kc * 2)      ) ^ swzn)) = q0;
            *(u32x4*)(lw + rowb + (((unsigned)(kc * 2) + 16u) ^ swzn)) = q1;
        }
        if (tid < 192) {  // scaled biases
            const int g = tid >> 6, o = tid & 63;
            const float* bg = (g == 0) ? b0g : (g == 1) ? b1g : b2g;
            lbias[tid] = bg[o] * C30;
        }
        if (tid < 208) {  // zero W3^T rows 3..15 (bytes 384..2047)
            u32x2 z; z[0] = 0u; z[1] = 0u;
            *(u32x2*)(lw3 + 384 + tid * 8) = z;
        }
        if (tid < 64) {
            const int k = tid;
            #pragma unroll
            for (int c = 0; c < 3; ++c) {    // W3 (not scaled: no sin after)
                unsigned short v = bfr(W3g[k * 3 + c]);
                *(unsigned short*)(lw3 + (unsigned)c * 128u +
                                   (((unsigned)(2 * k)) ^ ((unsigned)c << 4))) = v;
            }
            // layer-0 expanded row n=k: [Wh0..2,0, Wh0..2,0, Wl0..2,0, 0,0,0,0]
            unsigned short wh[3], wl[3];
            #pragma unroll
            for (int i = 0; i < 3; ++i) {
                float ws = W0g[i * 64 + k] * C30;
                wh[i] = bfr(ws);
                wl[i] = bfr(ws - bf2f(wh[i]));
            }
            u32x4 r0 = { (unsigned)wh[0] | ((unsigned)wh[1] << 16),
                         (unsigned)wh[2],
                         (unsigned)wh[0] | ((unsigned)wh[1] << 16),
                         (unsigned)wh[2] };
            u32x4 r1 = { (unsigned)wl[0] | ((unsigned)wl[1] << 16),
                         (unsigned)wl[2], 0u, 0u };
            *(u32x4*)(lw0 + k * 32)      = r0;
            *(u32x4*)(lw0 + k * 32 + 16) = r1;
        }
    }
    __syncthreads();
    // No further barriers: each wave only touches its own 64 rows of lh.

    const float* const xg = inp + (size_t)idx * (TPTS * 3);
    float*       const og = out + (size_t)bid * (TPTS * 3);
    const int tw = wid * 64;
    const unsigned swz = (unsigned)(l15 & 7) << 4;

    #pragma unroll 1
    for (int tile = 0; tile < 4; ++tile) {
        const int tbase = tile * 256 + tw;

        // ---------------- layer 0: x (f32, hi/lo split) -> h0 ----------------
        s16x8 xf[4];
        #pragma unroll
        for (int tj = 0; tj < 4; ++tj) {
            const float* xr = xg + (size_t)(tbase + tj * 16 + l15) * 3;
            float x0 = xr[0], x1 = xr[1], x2 = xr[2];
            unsigned short h0 = bfr(x0), h1 = bfr(x1), h2 = bfr(x2);
            unsigned short g0 = bfr(x0 - bf2f(h0));
            unsigned short g1 = bfr(x1 - bf2f(h1));
            unsigned short g2 = bfr(x2 - bf2f(h2));
            const bool hi = (kg < 2), lo = (kg == 0);
            s16x8 v;
            v[0] = hi ? (short)h0 : (short)0;
            v[1] = hi ? (short)h1 : (short)0;
            v[2] = hi ? (short)h2 : (short)0;
            v[3] = 0;
            v[4] = lo ? (short)g0 : (short)0;
            v[5] = lo ? (short)g1 : (short)0;
            v[6] = lo ? (short)g2 : (short)0;
            v[7] = 0;
            xf[tj] = v;
        }
        f32x4 acc[4][4];
        #pragma unroll
        for (int ni = 0; ni < 4; ++ni) {
            f32x4 bv = *(const f32x4*)(lbias + ni * 16 + kg * 4);
            #pragma unroll
            for (int tj = 0; tj < 4; ++tj) acc[ni][tj] = bv;
        }
        #pragma unroll
        for (int ni = 0; ni < 4; ++ni) {
            // kg>=2 lanes re-read k0..15 (their x-frag is zero -> contributes 0)
            const s16x8 wf = *(const s16x8*)(lw0 + (ni * 16 + l15) * 32 + (kg & 1) * 16);
            #pragma unroll
            for (int tj = 0; tj < 4; ++tj)
                acc[ni][tj] = __builtin_amdgcn_mfma_f32_16x16x32_bf16(
                    wf, xf[tj], acc[ni][tj], 0, 0, 0);
        }
        act_store(acc, lh, tw, l15, kg);

        // ---------------- layers 1, 2 ----------------
        hidden_layer(acc, lw1, lh, lbias + 64, tw, l15, kg);
        act_store(acc, lh, tw, l15, kg);
        hidden_layer(acc, lw2, lh, lbias + 128, tw, l15, kg);
        act_store(acc, lh, tw, l15, kg);

        // ---------------- layer 3: h2 @ W3 + b3 -> out ----------------
        {
            const float bb0 = b3g[0], bb1 = b3g[1], bb2 = b3g[2];
            f32x4 acc3[4];
            #pragma unroll
            for (int tj = 0; tj < 4; ++tj) {
                f32x4 c; c[0] = bb0; c[1] = bb1; c[2] = bb2; c[3] = 0.0f;
                acc3[tj] = c;
            }
            #pragma unroll
            for (int ks = 0; ks < 2; ++ks) {
                const unsigned ko = (unsigned)(ks * 64 + kg * 16);
                const s16x8 wf = *(const s16x8*)(lw3 + l15 * 128 + (ko ^ swz));
                #pragma unroll
                for (int tj = 0; tj < 4; ++tj) {
                    const s16x8 hf = *(const s16x8*)(lh + (tw + tj * 16 + l15) * 128 + (ko ^ swz));
                    acc3[tj] = __builtin_amdgcn_mfma_f32_16x16x32_bf16(
                        wf, hf, acc3[tj], 0, 0, 0);
                }
            }
            if (kg == 0) {  // lanes 0..15 hold n = 0..3 in regs 0..3
                #pragma unroll
                for (int tj = 0; tj < 4; ++tj) {
                    float* o = og + (size_t)(tbase + tj * 16 + l15) * 3;
                    o[0] = acc3[tj][0];
                    o[1] = acc3[tj][1];
                    o[2] = acc3[tj][2];
                }
            }
        }
    }
}

extern "C" void kernel_launch(void* const* d_in, const int* in_sizes, int n_in,
                              void* d_out, int out_size, void* d_ws, size_t ws_size,
                              hipStream_t stream) {
    (void)in_sizes; (void)n_in; (void)out_size; (void)d_ws; (void)ws_size;
    siren_fused<<<dim3(2048), dim3(256), 0, stream>>>(
        (const float*)d_in[0], (const int*)d_in[1],
        (const float*)d_in[2], (const float*)d_in[3],
        (const float*)d_in[4], (const float*)d_in[5],
        (const float*)d_in[6], (const float*)d_in[7],
        (const float*)d_in[8], (const float*)d_in[9],
        (float*)d_out);
}

// Round 3
// 249.172 us; speedup vs baseline: 1.0618x; 1.0618x over previous
//
#include <hip/hip_runtime.h>
#include <hip/hip_bf16.h>

// AdaptiveMultiSiren: 2048 blocks x 1024 coords, 3->64->64->64->3, sin(30*) acts.
// Layers 1,2 via bf16 MFMA (f32 accum); layer 0 via bf16 hi/lo split MFMA;
// layer 3 bf16 MFMA. omega0/(2*pi) folded into staged weights/biases so
// activation = fract + v_sin (revolutions).
// R1: 128-coord t-tiles -> LDS 54KB -> 37.6KB -> 4 WGs/CU (occupancy 2x).
// R2: identical resubmit (R2 bench was a broker acquisition timeout, no data).

namespace {

constexpr int   TPTS = 1024;
constexpr float C30  = 30.0f * 0.15915494309189535f; // omega0 / (2*pi)

typedef float        f32x4 __attribute__((ext_vector_type(4)));
typedef short        s16x8 __attribute__((ext_vector_type(8)));
typedef unsigned int u32x4 __attribute__((ext_vector_type(4)));
typedef unsigned int u32x2 __attribute__((ext_vector_type(2)));

__device__ __forceinline__ unsigned short bfr(float x) {
    __hip_bfloat16 h = __float2bfloat16(x);
    unsigned short u;
    __builtin_memcpy(&u, &h, sizeof(u));
    return u;
}
__device__ __forceinline__ float bf2f(unsigned short u) {
    unsigned int w = (unsigned int)u << 16;
    float f;
    __builtin_memcpy(&f, &w, sizeof(f));
    return f;
}
// input in revolutions; v_sin computes sin(2*pi*x), fract keeps it in-range
__device__ __forceinline__ float sin_rev(float r) {
    return __builtin_amdgcn_sinf(__builtin_amdgcn_fractf(r));
}

// acc[ni][tj]: D[n][t] frags. Apply sin, pack 4 consecutive n as bf16, store to
// swizzled row-major lh[t][n].
__device__ __forceinline__ void act_store(const f32x4 (&acc)[4][2],
                                          unsigned char* lh,
                                          int tw, int l15, int kg) {
    const unsigned swz = (unsigned)(l15 & 7) << 4;
    #pragma unroll
    for (int ni = 0; ni < 4; ++ni) {
        #pragma unroll
        for (int tj = 0; tj < 2; ++tj) {
            f32x4 a = acc[ni][tj];
            unsigned short s0 = bfr(sin_rev(a[0]));
            unsigned short s1 = bfr(sin_rev(a[1]));
            unsigned short s2 = bfr(sin_rev(a[2]));
            unsigned short s3 = bfr(sin_rev(a[3]));
            u32x2 p;
            p[0] = (unsigned)s0 | ((unsigned)s1 << 16);
            p[1] = (unsigned)s2 | ((unsigned)s3 << 16);
            const int trow = tw + tj * 16 + l15;
            *(u32x2*)(lh + trow * 128 +
                      (((unsigned)(ni * 32 + kg * 8)) ^ swz)) = p;
        }
    }
}

// z[n][t] = C30*b[n] + sum_k Wt[n][k] * h[t][k]   (both staged bf16 in LDS)
__device__ __forceinline__ void hidden_layer(f32x4 (&acc)[4][2],
                                             const unsigned char* lw,
                                             const unsigned char* lh,
                                             const float* lb,
                                             int tw, int l15, int kg) {
    const unsigned swz = (unsigned)(l15 & 7) << 4;
    #pragma unroll
    for (int ni = 0; ni < 4; ++ni) {
        f32x4 bv = *(const f32x4*)(lb + ni * 16 + kg * 4);
        #pragma unroll
        for (int tj = 0; tj < 2; ++tj) acc[ni][tj] = bv;
    }
    #pragma unroll
    for (int ks = 0; ks < 2; ++ks) {
        const unsigned ko = (unsigned)(ks * 64 + kg * 16);
        s16x8 wf[4], hf[2];
        #pragma unroll
        for (int ni = 0; ni < 4; ++ni)
            wf[ni] = *(const s16x8*)(lw + (ni * 16 + l15) * 128 + (ko ^ swz));
        #pragma unroll
        for (int tj = 0; tj < 2; ++tj)
            hf[tj] = *(const s16x8*)(lh + (tw + tj * 16 + l15) * 128 + (ko ^ swz));
        #pragma unroll
        for (int ni = 0; ni < 4; ++ni) {
            #pragma unroll
            for (int tj = 0; tj < 2; ++tj)
                acc[ni][tj] = __builtin_amdgcn_mfma_f32_16x16x32_bf16(
                    wf[ni], hf[tj], acc[ni][tj], 0, 0, 0);
        }
    }
}

} // namespace

__global__ __launch_bounds__(256, 4) void siren_fused(
    const float* __restrict__ inp, const int* __restrict__ indices,
    const float* __restrict__ W0, const float* __restrict__ b0,
    const float* __restrict__ W1, const float* __restrict__ b1,
    const float* __restrict__ W2, const float* __restrict__ b2,
    const float* __restrict__ W3, const float* __restrict__ b3,
    float* __restrict__ out)
{
    __shared__ __align__(16) unsigned char lds[37632];
    unsigned char* const lh  = lds;             // 128 x 128B : h tile (bf16, swz)
    unsigned char* const lw1 = lds + 16384;     // 64 x 128B  : C30*W1^T bf16, swz
    unsigned char* const lw2 = lds + 24576;     // 64 x 128B  : C30*W2^T bf16, swz
    unsigned char* const lw3 = lds + 32768;     // 16 x 128B  : W3^T bf16 (rows 0..2)
    unsigned char* const lw0 = lds + 34816;     // 64 x 32B   : layer0 hi/lo expand
    float*         const lbias = (float*)(lds + 36864); // 3 x 64 f32 (C30*b0,b1,b2)

    const int tid  = threadIdx.x;
    const int lane = tid & 63;
    const int wid  = tid >> 6;
    const int l15  = lane & 15;
    const int kg   = lane >> 4;
    const int bid  = blockIdx.x;

    const int idx = __builtin_amdgcn_readfirstlane(indices[bid]);

    const float* const W0g = W0 + (size_t)idx * 192;
    const float* const b0g = b0 + (size_t)idx * 64;
    const float* const W1g = W1 + (size_t)idx * 4096;
    const float* const b1g = b1 + (size_t)idx * 64;
    const float* const W2g = W2 + (size_t)idx * 4096;
    const float* const b2g = b2 + (size_t)idx * 64;
    const float* const W3g = W3 + (size_t)idx * 192;
    const float* const b3g = b3 + (size_t)idx * 3;

    // ------------- prologue: stage weights/biases to LDS -------------
    {
        const int n  = tid & 63;
        const int kc = (tid >> 6) * 16;          // k-chunk of 16
        const unsigned rowb = (unsigned)n * 128u;
        const unsigned swzn = (unsigned)(n & 7) << 4;
        #pragma unroll
        for (int w = 0; w < 2; ++w) {
            const float* Wg = w ? W2g : W1g;
            unsigned char* lw = w ? lw2 : lw1;
            unsigned int q[8];
            #pragma unroll
            for (int j = 0; j < 8; ++j) {
                unsigned short e0 = bfr(Wg[(kc + 2 * j    ) * 64 + n] * C30);
                unsigned short e1 = bfr(Wg[(kc + 2 * j + 1) * 64 + n] * C30);
                q[j] = (unsigned)e0 | ((unsigned)e1 << 16);
            }
            u32x4 q0 = {q[0], q[1], q[2], q[3]};
            u32x4 q1 = {q[4], q[5], q[6], q[7]};
            *(u32x4*)(lw + rowb + (((unsigned)(kc * 2)      ) ^ swzn)) = q0;
            *(u32x4*)(lw + rowb + (((unsigned)(kc * 2) + 16u) ^ swzn)) = q1;
        }
        if (tid < 192) {  // scaled biases
            const int g = tid >> 6, o = tid & 63;
            const float* bg = (g == 0) ? b0g : (g == 1) ? b1g : b2g;
            lbias[tid] = bg[o] * C30;
        }
        if (tid < 208) {  // zero W3^T rows 3..15 (bytes 384..2047)
            u32x2 z; z[0] = 0u; z[1] = 0u;
            *(u32x2*)(lw3 + 384 + tid * 8) = z;
        }
        if (tid < 64) {
            const int k = tid;
            #pragma unroll
            for (int c = 0; c < 3; ++c) {    // W3 (not scaled: no sin after)
                unsigned short v = bfr(W3g[k * 3 + c]);
                *(unsigned short*)(lw3 + (unsigned)c * 128u +
                                   (((unsigned)(2 * k)) ^ ((unsigned)c << 4))) = v;
            }
            // layer-0 expanded row n=k: [Wh0..2,0, Wh0..2,0, Wl0..2,0, 0,0,0,0]
            unsigned short wh[3], wl[3];
            #pragma unroll
            for (int i = 0; i < 3; ++i) {
                float ws = W0g[i * 64 + k] * C30;
                wh[i] = bfr(ws);
                wl[i] = bfr(ws - bf2f(wh[i]));
            }
            u32x4 r0 = { (unsigned)wh[0] | ((unsigned)wh[1] << 16),
                         (unsigned)wh[2],
                         (unsigned)wh[0] | ((unsigned)wh[1] << 16),
                         (unsigned)wh[2] };
            u32x4 r1 = { (unsigned)wl[0] | ((unsigned)wl[1] << 16),
                         (unsigned)wl[2], 0u, 0u };
            *(u32x4*)(lw0 + k * 32)      = r0;
            *(u32x4*)(lw0 + k * 32 + 16) = r1;
        }
    }
    __syncthreads();
    // No further barriers: each wave only touches its own 32 rows of lh.

    const float* const xg = inp + (size_t)idx * (TPTS * 3);
    float*       const og = out + (size_t)bid * (TPTS * 3);
    const int tw = wid * 32;
    const unsigned swz = (unsigned)(l15 & 7) << 4;

    #pragma unroll 1
    for (int tile = 0; tile < 8; ++tile) {
        const int tbase = tile * 128 + tw;

        // ---------------- layer 0: x (f32, hi/lo split) -> h0 ----------------
        s16x8 xf[2];
        #pragma unroll
        for (int tj = 0; tj < 2; ++tj) {
            const float* xr = xg + (size_t)(tbase + tj * 16 + l15) * 3;
            float x0 = xr[0], x1 = xr[1], x2 = xr[2];
            unsigned short h0 = bfr(x0), h1 = bfr(x1), h2 = bfr(x2);
            unsigned short g0 = bfr(x0 - bf2f(h0));
            unsigned short g1 = bfr(x1 - bf2f(h1));
            unsigned short g2 = bfr(x2 - bf2f(h2));
            const bool hi = (kg < 2), lo = (kg == 0);
            s16x8 v;
            v[0] = hi ? (short)h0 : (short)0;
            v[1] = hi ? (short)h1 : (short)0;
            v[2] = hi ? (short)h2 : (short)0;
            v[3] = 0;
            v[4] = lo ? (short)g0 : (short)0;
            v[5] = lo ? (short)g1 : (short)0;
            v[6] = lo ? (short)g2 : (short)0;
            v[7] = 0;
            xf[tj] = v;
        }
        f32x4 acc[4][2];
        #pragma unroll
        for (int ni = 0; ni < 4; ++ni) {
            f32x4 bv = *(const f32x4*)(lbias + ni * 16 + kg * 4);
            #pragma unroll
            for (int tj = 0; tj < 2; ++tj) acc[ni][tj] = bv;
        }
        #pragma unroll
        for (int ni = 0; ni < 4; ++ni) {
            // kg>=2 lanes re-read k0..15 (their x-frag is zero -> contributes 0)
            const s16x8 wf = *(const s16x8*)(lw0 + (ni * 16 + l15) * 32 + (kg & 1) * 16);
            #pragma unroll
            for (int tj = 0; tj < 2; ++tj)
                acc[ni][tj] = __builtin_amdgcn_mfma_f32_16x16x32_bf16(
                    wf, xf[tj], acc[ni][tj], 0, 0, 0);
        }
        act_store(acc, lh, tw, l15, kg);

        // ---------------- layers 1, 2 ----------------
        hidden_layer(acc, lw1, lh, lbias + 64, tw, l15, kg);
        act_store(acc, lh, tw, l15, kg);
        hidden_layer(acc, lw2, lh, lbias + 128, tw, l15, kg);
        act_store(acc, lh, tw, l15, kg);

        // ---------------- layer 3: h2 @ W3 + b3 -> out ----------------
        {
            const float bb0 = b3g[0], bb1 = b3g[1], bb2 = b3g[2];
            f32x4 acc3[2];
            #pragma unroll
            for (int tj = 0; tj < 2; ++tj) {
                f32x4 c; c[0] = bb0; c[1] = bb1; c[2] = bb2; c[3] = 0.0f;
                acc3[tj] = c;
            }
            #pragma unroll
            for (int ks = 0; ks < 2; ++ks) {
                const unsigned ko = (unsigned)(ks * 64 + kg * 16);
                const s16x8 wf = *(const s16x8*)(lw3 + l15 * 128 + (ko ^ swz));
                #pragma unroll
                for (int tj = 0; tj < 2; ++tj) {
                    const s16x8 hf = *(const s16x8*)(lh + (tw + tj * 16 + l15) * 128 + (ko ^ swz));
                    acc3[tj] = __builtin_amdgcn_mfma_f32_16x16x32_bf16(
                        wf, hf, acc3[tj], 0, 0, 0);
                }
            }
            if (kg == 0) {  // lanes 0..15 hold n = 0..3 in regs 0..3
                #pragma unroll
                for (int tj = 0; tj < 2; ++tj) {
                    float* o = og + (size_t)(tbase + tj * 16 + l15) * 3;
                    o[0] = acc3[tj][0];
                    o[1] = acc3[tj][1];
                    o[2] = acc3[tj][2];
                }
            }
        }
    }
}

extern "C" void kernel_launch(void* const* d_in, const int* in_sizes, int n_in,
                              void* d_out, int out_size, void* d_ws, size_t ws_size,
                              hipStream_t stream) {
    (void)in_sizes; (void)n_in; (void)out_size; (void)d_ws; (void)ws_size;
    siren_fused<<<dim3(2048), dim3(256), 0, stream>>>(
        (const float*)d_in[0], (const int*)d_in[1],
        (const float*)d_in[2], (const float*)d_in[3],
        (const float*)d_in[4], (const float*)d_in[5],
        (const float*)d_in[6], (const float*)d_in[7],
        (const float*)d_in[8], (const float*)d_in[9],
        (float*)d_out);
}

// Round 4
// 248.102 us; speedup vs baseline: 1.0664x; 1.0043x over previous
//
#include <hip/hip_runtime.h>
#include <hip/hip_bf16.h>

// AdaptiveMultiSiren: 2048 blocks x 1024 coords, 3->64->64->64->3, sin(30*) acts.
// Layers 1,2 via bf16 MFMA (f32 accum); layer 0 via bf16 hi/lo split MFMA;
// layer 3 bf16 MFMA. omega0/(2*pi) folded into staged weights/biases so
// activation = fract + v_sin (revolutions).
// R1: 128-coord t-tiles -> LDS 37.6KB -> 4 WGs/CU.
// R3 diagnosis: LDS pipe ~77% busy (46 b128 reads + 24 b64 writes per lane-tile)
//     -> this round: W1/W2 fragments hoisted to 64 persistent VGPRs (read once),
//        layer-0 bias folded into MFMA k-slots 3/7 (hi/lo vs constant 1.0).
//     LDS per lane-tile: 46r+24w -> 26r+24w.

namespace {

constexpr int   TPTS = 1024;
constexpr float C30  = 30.0f * 0.15915494309189535f; // omega0 / (2*pi)

typedef float        f32x4 __attribute__((ext_vector_type(4)));
typedef short        s16x8 __attribute__((ext_vector_type(8)));
typedef unsigned int u32x4 __attribute__((ext_vector_type(4)));
typedef unsigned int u32x2 __attribute__((ext_vector_type(2)));

__device__ __forceinline__ unsigned short bfr(float x) {
    __hip_bfloat16 h = __float2bfloat16(x);
    unsigned short u;
    __builtin_memcpy(&u, &h, sizeof(u));
    return u;
}
__device__ __forceinline__ float bf2f(unsigned short u) {
    unsigned int w = (unsigned int)u << 16;
    float f;
    __builtin_memcpy(&f, &w, sizeof(f));
    return f;
}
// input in revolutions; v_sin computes sin(2*pi*x), fract keeps it in-range
__device__ __forceinline__ float sin_rev(float r) {
    return __builtin_amdgcn_sinf(__builtin_amdgcn_fractf(r));
}

// acc[ni][tj]: D[n][t] frags. Apply sin, pack 4 consecutive n as bf16, store to
// swizzled row-major lh[t][n].
__device__ __forceinline__ void act_store(const f32x4 (&acc)[4][2],
                                          unsigned char* lh,
                                          int tw, int l15, int kg) {
    const unsigned swz = (unsigned)(l15 & 7) << 4;
    #pragma unroll
    for (int ni = 0; ni < 4; ++ni) {
        #pragma unroll
        for (int tj = 0; tj < 2; ++tj) {
            f32x4 a = acc[ni][tj];
            unsigned short s0 = bfr(sin_rev(a[0]));
            unsigned short s1 = bfr(sin_rev(a[1]));
            unsigned short s2 = bfr(sin_rev(a[2]));
            unsigned short s3 = bfr(sin_rev(a[3]));
            u32x2 p;
            p[0] = (unsigned)s0 | ((unsigned)s1 << 16);
            p[1] = (unsigned)s2 | ((unsigned)s3 << 16);
            const int trow = tw + tj * 16 + l15;
            *(u32x2*)(lh + trow * 128 +
                      (((unsigned)(ni * 32 + kg * 8)) ^ swz)) = p;
        }
    }
}

// z[n][t] = C30*b[n] + sum_k W[n][k] * h[t][k]; W frags in registers.
__device__ __forceinline__ void hidden_layer(f32x4 (&acc)[4][2],
                                             const s16x8 (&wf)[2][4],
                                             const unsigned char* lh,
                                             const float* lb,
                                             int tw, int l15, int kg) {
    const unsigned swz = (unsigned)(l15 & 7) << 4;
    #pragma unroll
    for (int ni = 0; ni < 4; ++ni) {
        f32x4 bv = *(const f32x4*)(lb + ni * 16 + kg * 4);
        #pragma unroll
        for (int tj = 0; tj < 2; ++tj) acc[ni][tj] = bv;
    }
    #pragma unroll
    for (int ks = 0; ks < 2; ++ks) {
        const unsigned ko = (unsigned)(ks * 64 + kg * 16);
        s16x8 hf[2];
        #pragma unroll
        for (int tj = 0; tj < 2; ++tj)
            hf[tj] = *(const s16x8*)(lh + (tw + tj * 16 + l15) * 128 + (ko ^ swz));
        #pragma unroll
        for (int ni = 0; ni < 4; ++ni) {
            #pragma unroll
            for (int tj = 0; tj < 2; ++tj)
                acc[ni][tj] = __builtin_amdgcn_mfma_f32_16x16x32_bf16(
                    wf[ks][ni], hf[tj], acc[ni][tj], 0, 0, 0);
        }
    }
}

} // namespace

__global__ __launch_bounds__(256, 4) void siren_fused(
    const float* __restrict__ inp, const int* __restrict__ indices,
    const float* __restrict__ W0, const float* __restrict__ b0,
    const float* __restrict__ W1, const float* __restrict__ b1,
    const float* __restrict__ W2, const float* __restrict__ b2,
    const float* __restrict__ W3, const float* __restrict__ b3,
    float* __restrict__ out)
{
    __shared__ __align__(16) unsigned char lds[37376];
    unsigned char* const lh  = lds;             // 128 x 128B : h tile (bf16, swz)
    unsigned char* const lw1 = lds + 16384;     // 64 x 128B  : C30*W1^T bf16, swz
    unsigned char* const lw2 = lds + 24576;     // 64 x 128B  : C30*W2^T bf16, swz
    unsigned char* const lw3 = lds + 32768;     // 16 x 128B  : W3^T bf16 (rows 0..2)
    unsigned char* const lw0 = lds + 34816;     // 64 x 32B   : L0 hi/lo + bias expand
    float*         const lbias = (float*)(lds + 36864); // 2 x 64 f32 (C30*b1,b2)

    const int tid  = threadIdx.x;
    const int lane = tid & 63;
    const int wid  = tid >> 6;
    const int l15  = lane & 15;
    const int kg   = lane >> 4;
    const int bid  = blockIdx.x;

    const int idx = __builtin_amdgcn_readfirstlane(indices[bid]);

    const float* const W0g = W0 + (size_t)idx * 192;
    const float* const b0g = b0 + (size_t)idx * 64;
    const float* const W1g = W1 + (size_t)idx * 4096;
    const float* const b1g = b1 + (size_t)idx * 64;
    const float* const W2g = W2 + (size_t)idx * 4096;
    const float* const b2g = b2 + (size_t)idx * 64;
    const float* const W3g = W3 + (size_t)idx * 192;
    const float* const b3g = b3 + (size_t)idx * 3;

    // ------------- prologue: stage weights/biases to LDS -------------
    {
        const int n  = tid & 63;
        const int kc = (tid >> 6) * 16;          // k-chunk of 16
        const unsigned rowb = (unsigned)n * 128u;
        const unsigned swzn = (unsigned)(n & 7) << 4;
        #pragma unroll
        for (int w = 0; w < 2; ++w) {
            const float* Wg = w ? W2g : W1g;
            unsigned char* lw = w ? lw2 : lw1;
            unsigned int q[8];
            #pragma unroll
            for (int j = 0; j < 8; ++j) {
                unsigned short e0 = bfr(Wg[(kc + 2 * j    ) * 64 + n] * C30);
                unsigned short e1 = bfr(Wg[(kc + 2 * j + 1) * 64 + n] * C30);
                q[j] = (unsigned)e0 | ((unsigned)e1 << 16);
            }
            u32x4 q0 = {q[0], q[1], q[2], q[3]};
            u32x4 q1 = {q[4], q[5], q[6], q[7]};
            *(u32x4*)(lw + rowb + (((unsigned)(kc * 2)      ) ^ swzn)) = q0;
            *(u32x4*)(lw + rowb + (((unsigned)(kc * 2) + 16u) ^ swzn)) = q1;
        }
        if (tid < 128) {  // scaled biases for layers 1,2
            const int g = tid >> 6, o = tid & 63;
            const float* bg = g ? b2g : b1g;
            lbias[tid] = bg[o] * C30;
        }
        if (tid < 208) {  // zero W3^T rows 3..15 (bytes 384..2047)
            u32x2 z; z[0] = 0u; z[1] = 0u;
            *(u32x2*)(lw3 + 384 + tid * 8) = z;
        }
        if (tid < 64) {
            const int k = tid;
            #pragma unroll
            for (int c = 0; c < 3; ++c) {    // W3 (not scaled: no sin after)
                unsigned short v = bfr(W3g[k * 3 + c]);
                *(unsigned short*)(lw3 + (unsigned)c * 128u +
                                   (((unsigned)(2 * k)) ^ ((unsigned)c << 4))) = v;
            }
            // layer-0 expanded row n=k:
            // r0 = [Wh0,Wh1,Wh2,Bhi, Wh0,Wh1,Wh2,Blo] ; r1 = [Wl0,Wl1,Wl2,0,...]
            // (bias rides k-slots 3 and 7 against constant-1.0 in the x frag)
            unsigned short wh[3], wl[3];
            #pragma unroll
            for (int i = 0; i < 3; ++i) {
                float ws = W0g[i * 64 + k] * C30;
                wh[i] = bfr(ws);
                wl[i] = bfr(ws - bf2f(wh[i]));
            }
            const float bs = b0g[k] * C30;
            unsigned short Bhi = bfr(bs);
            unsigned short Blo = bfr(bs - bf2f(Bhi));
            u32x4 r0 = { (unsigned)wh[0] | ((unsigned)wh[1] << 16),
                         (unsigned)wh[2] | ((unsigned)Bhi   << 16),
                         (unsigned)wh[0] | ((unsigned)wh[1] << 16),
                         (unsigned)wh[2] | ((unsigned)Blo   << 16) };
            u32x4 r1 = { (unsigned)wl[0] | ((unsigned)wl[1] << 16),
                         (unsigned)wl[2], 0u, 0u };
            *(u32x4*)(lw0 + k * 32)      = r0;
            *(u32x4*)(lw0 + k * 32 + 16) = r1;
        }
    }
    __syncthreads();
    // No further barriers: each wave only touches its own 32 rows of lh.

    const unsigned swz = (unsigned)(l15 & 7) << 4;

    // Hoist W1/W2 MFMA A-fragments into persistent registers (read LDS once,
    // reused across all 8 tiles): 16 x s16x8 = 64 VGPRs.
    s16x8 w1r[2][4], w2r[2][4];
    #pragma unroll
    for (int ks = 0; ks < 2; ++ks) {
        const unsigned ko = (unsigned)(ks * 64 + kg * 16);
        #pragma unroll
        for (int ni = 0; ni < 4; ++ni) {
            w1r[ks][ni] = *(const s16x8*)(lw1 + (ni * 16 + l15) * 128 + (ko ^ swz));
            w2r[ks][ni] = *(const s16x8*)(lw2 + (ni * 16 + l15) * 128 + (ko ^ swz));
        }
    }

    const float* const xg = inp + (size_t)idx * (TPTS * 3);
    float*       const og = out + (size_t)bid * (TPTS * 3);
    const int tw = wid * 32;

    #pragma unroll 1
    for (int tile = 0; tile < 8; ++tile) {
        const int tbase = tile * 128 + tw;

        // ---------------- layer 0: x (f32, hi/lo split) -> h0 ----------------
        s16x8 xf[2];
        #pragma unroll
        for (int tj = 0; tj < 2; ++tj) {
            const float* xr = xg + (size_t)(tbase + tj * 16 + l15) * 3;
            float x0 = xr[0], x1 = xr[1], x2 = xr[2];
            unsigned short h0 = bfr(x0), h1 = bfr(x1), h2 = bfr(x2);
            unsigned short g0 = bfr(x0 - bf2f(h0));
            unsigned short g1 = bfr(x1 - bf2f(h1));
            unsigned short g2 = bfr(x2 - bf2f(h2));
            const bool hi = (kg < 2), lo = (kg == 0);
            const short one = lo ? (short)0x3F80 : (short)0;  // bf16 1.0
            s16x8 v;
            v[0] = hi ? (short)h0 : (short)0;
            v[1] = hi ? (short)h1 : (short)0;
            v[2] = hi ? (short)h2 : (short)0;
            v[3] = one;          // * Bhi (k-slot 3)
            v[4] = lo ? (short)g0 : (short)0;
            v[5] = lo ? (short)g1 : (short)0;
            v[6] = lo ? (short)g2 : (short)0;
            v[7] = one;          // * Blo (k-slot 7)
            xf[tj] = v;
        }
        f32x4 acc[4][2];
        #pragma unroll
        for (int ni = 0; ni < 4; ++ni) {
            #pragma unroll
            for (int tj = 0; tj < 2; ++tj) {
                f32x4 z; z[0] = 0.f; z[1] = 0.f; z[2] = 0.f; z[3] = 0.f;
                acc[ni][tj] = z;
            }
        }
        #pragma unroll
        for (int ni = 0; ni < 4; ++ni) {
            // kg>=2 lanes re-read k0..15 (their x-frag is zero -> contributes 0)
            const s16x8 wf = *(const s16x8*)(lw0 + (ni * 16 + l15) * 32 + (kg & 1) * 16);
            #pragma unroll
            for (int tj = 0; tj < 2; ++tj)
                acc[ni][tj] = __builtin_amdgcn_mfma_f32_16x16x32_bf16(
                    wf, xf[tj], acc[ni][tj], 0, 0, 0);
        }
        act_store(acc, lh, tw, l15, kg);

        // ---------------- layers 1, 2 ----------------
        hidden_layer(acc, w1r, lh, lbias,      tw, l15, kg);
        act_store(acc, lh, tw, l15, kg);
        hidden_layer(acc, w2r, lh, lbias + 64, tw, l15, kg);
        act_store(acc, lh, tw, l15, kg);

        // ---------------- layer 3: h2 @ W3 + b3 -> out ----------------
        {
            const float bb0 = b3g[0], bb1 = b3g[1], bb2 = b3g[2];
            f32x4 acc3[2];
            #pragma unroll
            for (int tj = 0; tj < 2; ++tj) {
                f32x4 c; c[0] = bb0; c[1] = bb1; c[2] = bb2; c[3] = 0.0f;
                acc3[tj] = c;
            }
            #pragma unroll
            for (int ks = 0; ks < 2; ++ks) {
                const unsigned ko = (unsigned)(ks * 64 + kg * 16);
                const s16x8 wf = *(const s16x8*)(lw3 + l15 * 128 + (ko ^ swz));
                #pragma unroll
                for (int tj = 0; tj < 2; ++tj) {
                    const s16x8 hf = *(const s16x8*)(lh + (tw + tj * 16 + l15) * 128 + (ko ^ swz));
                    acc3[tj] = __builtin_amdgcn_mfma_f32_16x16x32_bf16(
                        wf, hf, acc3[tj], 0, 0, 0);
                }
            }
            if (kg == 0) {  // lanes 0..15 hold n = 0..3 in regs 0..3
                #pragma unroll
                for (int tj = 0; tj < 2; ++tj) {
                    float* o = og + (size_t)(tbase + tj * 16 + l15) * 3;
                    o[0] = acc3[tj][0];
                    o[1] = acc3[tj][1];
                    o[2] = acc3[tj][2];
                }
            }
        }
    }
}

extern "C" void kernel_launch(void* const* d_in, const int* in_sizes, int n_in,
                              void* d_out, int out_size, void* d_ws, size_t ws_size,
                              hipStream_t stream) {
    (void)in_sizes; (void)n_in; (void)out_size; (void)d_ws; (void)ws_size;
    siren_fused<<<dim3(2048), dim3(256), 0, stream>>>(
        (const float*)d_in[0], (const int*)d_in[1],
        (const float*)d_in[2], (const float*)d_in[3],
        (const float*)d_in[4], (const float*)d_in[5],
        (const float*)d_in[6], (const float*)d_in[7],
        (const float*)d_in[8], (const float*)d_in[9],
        (float*)d_out);
}